// Round 1
// baseline (203.209 us; speedup 1.0000x reference)
//
#include <hip/hip_runtime.h>

// ShiftAwareAttention1D — algebraic collapse.
//
// The reference's grid_sample input has width W=1, and the learned offsets go
// into the x (width) coordinate: x = (grid+1)*0.5*(W-1) == 0 always. The y
// coordinate is the constant 0 -> y = (L-1)/2 = 1023.5, so every (l, p)
// samples 0.5*(v[...,1023] + v[...,1024]). Softmax weights sum to 1, so the
// aggregation is a no-op. The entire op reduces to two per-batch 1024x1024
// GEMVs and a broadcast of one 1024-vector per batch across L positions.

#define BB 8
#define LL 2048
#define DD 1024

typedef float f32x4 __attribute__((ext_vector_type(4)));

// ---------------------------------------------------------------------------
// Kernel 1: vproj[b][d] = sum_k Wv[d][k] * 0.5*(value[b][1023][k]+value[b][1024][k]) + bv[d]
// One wave per output row d; 8 batch accumulators per lane; butterfly reduce.
// ---------------------------------------------------------------------------
__global__ __launch_bounds__(64) void k_vproj(const float* __restrict__ value,
                                              const float* __restrict__ Wv,
                                              const float* __restrict__ bv,
                                              float* __restrict__ vproj) {
    const int d = blockIdx.x;
    const int lane = threadIdx.x;
    const f32x4* W4 = (const f32x4*)(Wv + (size_t)d * DD);

    float acc[BB];
#pragma unroll
    for (int b = 0; b < BB; ++b) acc[b] = 0.f;

#pragma unroll
    for (int i = 0; i < 4; ++i) {
        const int k4 = lane + 64 * i;           // float4 index within the row
        const f32x4 w = W4[k4];
#pragma unroll
        for (int b = 0; b < BB; ++b) {
            const f32x4* p = (const f32x4*)(value + ((size_t)b * LL + 1023) * DD);
            const f32x4 v0 = p[k4];             // row 1023
            const f32x4 v1 = p[k4 + DD / 4];    // row 1024 (+256 float4)
            const f32x4 u = 0.5f * (v0 + v1);
            acc[b] += w.x * u.x + w.y * u.y + w.z * u.z + w.w * u.w;
        }
    }

#pragma unroll
    for (int off = 32; off >= 1; off >>= 1) {
#pragma unroll
        for (int b = 0; b < BB; ++b) acc[b] += __shfl_xor(acc[b], off, 64);
    }

    if (lane == 0) {
        const float bias = bv[d];
#pragma unroll
        for (int b = 0; b < BB; ++b) vproj[(size_t)b * DD + d] = acc[b] + bias;
    }
}

// ---------------------------------------------------------------------------
// Kernel 2: orow[b][d] = sum_k Wout[d][k] * vproj[b][k] + bout[d]
// ---------------------------------------------------------------------------
__global__ __launch_bounds__(64) void k_orow(const float* __restrict__ vproj,
                                             const float* __restrict__ Wout,
                                             const float* __restrict__ bout,
                                             float* __restrict__ orow) {
    const int d = blockIdx.x;
    const int lane = threadIdx.x;
    const f32x4* W4 = (const f32x4*)(Wout + (size_t)d * DD);
    const f32x4* in4 = (const f32x4*)vproj;

    float acc[BB];
#pragma unroll
    for (int b = 0; b < BB; ++b) acc[b] = 0.f;

#pragma unroll
    for (int i = 0; i < 4; ++i) {
        const int k4 = lane + 64 * i;
        const f32x4 w = W4[k4];
#pragma unroll
        for (int b = 0; b < BB; ++b) {
            const f32x4 v = in4[b * (DD / 4) + k4];
            acc[b] += w.x * v.x + w.y * v.y + w.z * v.z + w.w * v.w;
        }
    }

#pragma unroll
    for (int off = 32; off >= 1; off >>= 1) {
#pragma unroll
        for (int b = 0; b < BB; ++b) acc[b] += __shfl_xor(acc[b], off, 64);
    }

    if (lane == 0) {
        const float bias = bout[d];
#pragma unroll
        for (int b = 0; b < BB; ++b) orow[(size_t)b * DD + d] = acc[b] + bias;
    }
}

// ---------------------------------------------------------------------------
// Kernel 3: out[b][l][:] = orow[b][:]   — 64 MiB HBM write, the roofline term.
// float4 nontemporal stores; orow reads are L1/L2 hits (32 KiB total).
// ---------------------------------------------------------------------------
__global__ __launch_bounds__(256) void k_bcast(const float* __restrict__ orow,
                                               float* __restrict__ out) {
    const f32x4* o4 = (const f32x4*)orow;     // (B, 256)
    f32x4* out4 = (f32x4*)out;                // (B*L*256)
    const size_t total = (size_t)BB * LL * (DD / 4);   // 4,194,304
    const size_t stride = (size_t)gridDim.x * blockDim.x;
    for (size_t i = (size_t)blockIdx.x * blockDim.x + threadIdx.x; i < total; i += stride) {
        const int b  = (int)(i >> 19);        // / (L*D/4) = 2^19
        const int d4 = (int)(i & (DD / 4 - 1));
        __builtin_nontemporal_store(o4[b * (DD / 4) + d4], &out4[i]);
    }
}

extern "C" void kernel_launch(void* const* d_in, const int* in_sizes, int n_in,
                              void* d_out, int out_size, void* d_ws, size_t ws_size,
                              hipStream_t stream) {
    // setup_inputs order: query, key_in, value, Wv, bv, Woff, boff, Ww, bw, Wout, bout
    const float* value = (const float*)d_in[2];
    const float* Wv    = (const float*)d_in[3];
    const float* bv    = (const float*)d_in[4];
    const float* Wout  = (const float*)d_in[9];
    const float* bout  = (const float*)d_in[10];
    float* out = (float*)d_out;

    float* vproj = (float*)d_ws;          // B*D floats = 32 KiB
    float* orow  = vproj + BB * DD;       // B*D floats = 32 KiB

    k_vproj<<<DD, 64, 0, stream>>>(value, Wv, bv, vproj);
    k_orow <<<DD, 64, 0, stream>>>(vproj, Wout, bout, orow);
    k_bcast<<<2048, 256, 0, stream>>>(orow, out);
}